// Round 2
// baseline (491.229 us; speedup 1.0000x reference)
//
#include <hip/hip_runtime.h>
#include <hip/hip_bf16.h>
#include <stdint.h>

#define N_NODES 50000
#define N_EDGES 800000
#define NFEAT 512
#define NHID 512
#define NCLASS 128
#define MPAD 50048   // 391 * 128

typedef short short8 __attribute__((ext_vector_type(8)));
typedef float f32x4 __attribute__((ext_vector_type(4)));

__device__ __forceinline__ ushort f2bf(float f) {
  union { float f; uint32_t u; } v; v.f = f;
  uint32_t u = v.u;
  uint32_t r = (u + 0x7fffu + ((u >> 16) & 1u)) >> 16;  // RNE
  return (ushort)r;
}
__device__ __forceinline__ float bf2f(ushort h) {
  union { uint32_t u; float f; } v; v.u = ((uint32_t)h) << 16;
  return v.f;
}

// ---------------- conversions ----------------
__global__ __launch_bounds__(256) void k_convert_x(const float* __restrict__ x,
                                                   ushort* __restrict__ xb) {
  long gid = (long)blockIdx.x * blockDim.x + threadIdx.x;
  long idx = gid * 8;
  if (idx >= (long)MPAD * NFEAT) return;
  int row = (int)(idx >> 9);
  short8 o;
  if (row < N_NODES) {
    const float4* p = (const float4*)(x + idx);
    float4 a = p[0], b = p[1];
    o[0] = f2bf(a.x); o[1] = f2bf(a.y); o[2] = f2bf(a.z); o[3] = f2bf(a.w);
    o[4] = f2bf(b.x); o[5] = f2bf(b.y); o[6] = f2bf(b.z); o[7] = f2bf(b.w);
  } else {
    o = (short8)0;   // zero pad rows
  }
  *(short8*)(xb + idx) = o;
}

__global__ __launch_bounds__(256) void k_convert(const float* __restrict__ in,
                                                 ushort* __restrict__ out, int n8) {
  int gid = blockIdx.x * blockDim.x + threadIdx.x;
  if (gid >= n8) return;
  long idx = (long)gid * 8;
  const float4* p = (const float4*)(in + idx);
  float4 a = p[0], b = p[1];
  short8 o;
  o[0] = f2bf(a.x); o[1] = f2bf(a.y); o[2] = f2bf(a.z); o[3] = f2bf(a.w);
  o[4] = f2bf(b.x); o[5] = f2bf(b.y); o[6] = f2bf(b.z); o[7] = f2bf(b.w);
  *(short8*)(out + idx) = o;
}

// ---------------- CSR build ----------------
__global__ __launch_bounds__(256) void k_hist(const int* __restrict__ src,
                                              int* __restrict__ deg) {
  int e = blockIdx.x * blockDim.x + threadIdx.x;
  if (e < N_EDGES) atomicAdd(&deg[src[e]], 1);
}

__global__ __launch_bounds__(1024) void k_scan(const int* __restrict__ deg,
                                               int* __restrict__ rp,
                                               int* __restrict__ cur) {
  __shared__ int wsum[16];
  __shared__ int stot;
  int t = threadIdx.x;
  int lane = t & 63, wv = t >> 6;
  int running = 0;
  for (int base = 0; base < N_NODES; base += 1024) {
    int i = base + t;
    int v = (i < N_NODES) ? deg[i] : 0;
    int sc = v;
    #pragma unroll
    for (int off = 1; off < 64; off <<= 1) {
      int u = __shfl_up(sc, off, 64);
      if (lane >= off) sc += u;
    }
    if (lane == 63) wsum[wv] = sc;
    __syncthreads();
    if (wv == 0) {
      int s = (lane < 16) ? wsum[lane] : 0;
      #pragma unroll
      for (int off = 1; off < 16; off <<= 1) {
        int u = __shfl_up(s, off, 64);
        if (lane >= off) s += u;
      }
      if (lane < 16) wsum[lane] = s;
      if (lane == 15) stot = s;
    }
    __syncthreads();
    int woff = (wv == 0) ? 0 : wsum[wv - 1];
    int excl = running + woff + sc - v;
    if (i < N_NODES) { rp[i] = excl; cur[i] = excl; }
    running += stot;
    __syncthreads();   // protect wsum/stot before next chunk
  }
  if (t == 0) rp[N_NODES] = running;
}

__global__ __launch_bounds__(256) void k_fill(const int* __restrict__ src,
                                              const int* __restrict__ dst,
                                              const float* __restrict__ w,
                                              int* __restrict__ cur,
                                              int* __restrict__ sdst,
                                              float* __restrict__ sw) {
  int e = blockIdx.x * blockDim.x + threadIdx.x;
  if (e < N_EDGES) {
    int s = src[e];
    int pos = atomicAdd(&cur[s], 1);
    sdst[pos] = dst[e];
    sw[pos] = w[e];
  }
}

// ---------------- GEMM: C = A @ B^T + bias (bf16 in/out, f32 acc) ----------------
// A [M][K] bf16 row-major (M = MPAD), B [Nout][K] bf16 row-major (torch Linear weight)
// tile 128x128, BK=64, 256 threads (4 waves, 2x2), each wave 64x64 = 4x4 frags.
__global__ __launch_bounds__(256) void k_gemm_bt(const ushort* __restrict__ A,
                                                 const ushort* __restrict__ B,
                                                 const float* __restrict__ bias,
                                                 ushort* __restrict__ C,
                                                 int K, int Nout) {
  __shared__ ushort sA[128 * 64];
  __shared__ ushort sB[128 * 64];
  const int t = threadIdx.x;
  const int lane = t & 63;
  const int wave = t >> 6;
  const int wr = wave >> 1, wc = wave & 1;
  const int bm = blockIdx.x, bn = blockIdx.y;

  f32x4 acc[4][4];
  #pragma unroll
  for (int i = 0; i < 4; i++)
    #pragma unroll
    for (int j = 0; j < 4; j++) acc[i][j] = (f32x4)0.f;

  const long a_base = (long)bm * 128 * K;
  const long b_base = (long)bn * 128 * K;

  for (int kt = 0; kt < K; kt += 64) {
    // stage A and B tiles (each 128 rows x 64 bf16 = 16KB, 1024 x 16B chunks)
    #pragma unroll
    for (int it = 0; it < 4; ++it) {
      int c = it * 256 + t;           // chunk 0..1023
      int r = c >> 3, cc = c & 7;     // row, 16B-chunk within row
      int swz = (cc * 16) ^ ((r & 7) << 4);
      float4 va = *(const float4*)(A + a_base + (long)r * K + kt + cc * 8);
      *(float4*)((char*)sA + r * 128 + swz) = va;
      float4 vb = *(const float4*)(B + b_base + (long)r * K + kt + cc * 8);
      *(float4*)((char*)sB + r * 128 + swz) = vb;
    }
    __syncthreads();
    #pragma unroll
    for (int kk = 0; kk < 2; ++kk) {
      short8 af[4], bfr[4];
      int kchunk = kk * 4 + (lane >> 4);
      #pragma unroll
      for (int mr = 0; mr < 4; ++mr) {
        int row = wr * 64 + mr * 16 + (lane & 15);
        af[mr] = *(const short8*)((const char*)sA + row * 128 +
                                  ((kchunk * 16) ^ ((row & 7) << 4)));
      }
      #pragma unroll
      for (int nr = 0; nr < 4; ++nr) {
        int row = wc * 64 + nr * 16 + (lane & 15);
        bfr[nr] = *(const short8*)((const char*)sB + row * 128 +
                                   ((kchunk * 16) ^ ((row & 7) << 4)));
      }
      #pragma unroll
      for (int mr = 0; mr < 4; ++mr)
        #pragma unroll
        for (int nr = 0; nr < 4; ++nr)
          acc[mr][nr] = __builtin_amdgcn_mfma_f32_16x16x32_bf16(af[mr], bfr[nr],
                                                                acc[mr][nr], 0, 0, 0);
    }
    __syncthreads();
  }

  // epilogue: +bias, bf16 store. C/D layout: col = lane&15, row = (lane>>4)*4 + reg
  #pragma unroll
  for (int mr = 0; mr < 4; ++mr)
    #pragma unroll
    for (int nr = 0; nr < 4; ++nr) {
      int col = bn * 128 + wc * 64 + nr * 16 + (lane & 15);
      float bv = bias[col];
      #pragma unroll
      for (int reg = 0; reg < 4; ++reg) {
        int row = bm * 128 + wr * 64 + mr * 16 + (lane >> 4) * 4 + reg;
        C[(long)row * Nout + col] = f2bf(acc[mr][nr][reg] + bv);
      }
    }
}

// ---------------- SpMM layer 1 (+ReLU), bf16 out ----------------
__global__ __launch_bounds__(256) void k_spmm1(const int* __restrict__ rp,
                                               const int* __restrict__ sdst,
                                               const float* __restrict__ sw,
                                               const ushort* __restrict__ c1,
                                               ushort* __restrict__ h) {
  int i = blockIdx.x;          // node (covers MPAD; pad rows -> zeros)
  int t = threadIdx.x;         // 256 threads, 2 feats each
  float a0 = 0.f, a1 = 0.f;
  if (i < N_NODES) {
    int beg = rp[i], end = rp[i + 1];
    for (int j = beg; j < end; ++j) {
      int d = sdst[j];
      float w = sw[j];
      uint32_t v = *(const uint32_t*)(c1 + (long)d * NHID + 2 * t);
      a0 += w * bf2f((ushort)(v & 0xffffu));
      a1 += w * bf2f((ushort)(v >> 16));
    }
  }
  a0 = a0 > 0.f ? a0 : 0.f;
  a1 = a1 > 0.f ? a1 : 0.f;
  uint32_t o = (uint32_t)f2bf(a0) | ((uint32_t)f2bf(a1) << 16);
  *(uint32_t*)(h + (long)i * NHID + 2 * t) = o;
}

// ---------------- SpMM layer 2, f32 out ----------------
__global__ __launch_bounds__(128) void k_spmm2(const int* __restrict__ rp,
                                               const int* __restrict__ sdst,
                                               const float* __restrict__ sw,
                                               const ushort* __restrict__ c2,
                                               float* __restrict__ out) {
  int i = blockIdx.x;          // node < N_NODES
  int t = threadIdx.x;         // 128 threads, 1 class each
  float a = 0.f;
  int beg = rp[i], end = rp[i + 1];
  for (int j = beg; j < end; ++j) {
    a += sw[j] * bf2f(c2[(long)sdst[j] * NCLASS + t]);
  }
  out[(long)i * NCLASS + t] = a;
}

extern "C" void kernel_launch(void* const* d_in, const int* in_sizes, int n_in,
                              void* d_out, int out_size, void* d_ws, size_t ws_size,
                              hipStream_t stream) {
  const float* x    = (const float*)d_in[0];
  const float* ew   = (const float*)d_in[1];
  const float* W1   = (const float*)d_in[2];
  const float* b1   = (const float*)d_in[3];
  const float* W2   = (const float*)d_in[4];
  const float* b2   = (const float*)d_in[5];
  const int*   esrc = (const int*)d_in[6];
  const int*   edst = (const int*)d_in[7];
  float* out = (float*)d_out;

  char* ws = (char*)d_ws;
  size_t off = 0;
  auto alloc = [&](size_t bytes) -> void* {
    void* p = ws + off;
    off = (off + bytes + 255) & ~(size_t)255;
    return p;
  };

  ushort* buf0 = (ushort*)alloc((size_t)MPAD * 512 * 2);  // x_bf16, later h_bf16
  ushort* buf1 = (ushort*)alloc((size_t)MPAD * 512 * 2);  // c1_bf16, later c2_bf16
  ushort* w1b  = (ushort*)alloc((size_t)512 * 512 * 2);
  ushort* w2b  = (ushort*)alloc((size_t)128 * 512 * 2);
  int*    deg  = (int*)alloc((size_t)(N_NODES + 1) * 4);
  int*    rp   = (int*)alloc((size_t)(N_NODES + 1) * 4);
  int*    cur  = (int*)alloc((size_t)N_NODES * 4);
  int*    sdst = (int*)alloc((size_t)N_EDGES * 4);
  float*  sw   = (float*)alloc((size_t)N_EDGES * 4);

  // CSR build
  hipMemsetAsync(deg, 0, (size_t)N_NODES * 4, stream);
  k_hist<<<(N_EDGES + 255) / 256, 256, 0, stream>>>(esrc, deg);
  k_scan<<<1, 1024, 0, stream>>>(deg, rp, cur);
  k_fill<<<(N_EDGES + 255) / 256, 256, 0, stream>>>(esrc, edst, ew, cur, sdst, sw);

  // bf16 conversions
  k_convert_x<<<(MPAD * NFEAT / 8 + 255) / 256, 256, 0, stream>>>(x, buf0);
  k_convert<<<(512 * 512 / 8 + 255) / 256, 256, 0, stream>>>(W1, w1b, 512 * 512 / 8);
  k_convert<<<(128 * 512 / 8 + 255) / 256, 256, 0, stream>>>(W2, w2b, 128 * 512 / 8);

  // layer 1: linear -> spmm -> relu
  dim3 g1(MPAD / 128, NHID / 128);
  k_gemm_bt<<<g1, 256, 0, stream>>>(buf0, w1b, b1, buf1, NFEAT, NHID);
  k_spmm1<<<MPAD, 256, 0, stream>>>(rp, sdst, sw, buf1, buf0);

  // layer 2: linear -> spmm
  dim3 g2(MPAD / 128, NCLASS / 128);
  k_gemm_bt<<<g2, 256, 0, stream>>>(buf0, w2b, b2, buf1, NHID, NCLASS);
  k_spmm2<<<N_NODES, 128, 0, stream>>>(rp, sdst, sw, buf1, out);
}

// Round 3
// 425.464 us; speedup vs baseline: 1.1546x; 1.1546x over previous
//
#include <hip/hip_runtime.h>
#include <hip/hip_bf16.h>
#include <hip/hip_fp8.h>
#include <stdint.h>

#define N_NODES 50000
#define N_EDGES 800000
#define NFEAT 512
#define NHID 512
#define NCLASS 128
#define MPAD 50048   // 391 * 128

typedef short short8 __attribute__((ext_vector_type(8)));
typedef float f32x4 __attribute__((ext_vector_type(4)));
typedef float f32x2 __attribute__((ext_vector_type(2)));

__device__ __forceinline__ ushort f2bf(float f) {
  union { float f; uint32_t u; } v; v.f = f;
  uint32_t u = v.u;
  uint32_t r = (u + 0x7fffu + ((u >> 16) & 1u)) >> 16;  // RNE
  return (ushort)r;
}
__device__ __forceinline__ float bf2f(ushort h) {
  union { uint32_t u; float f; } v; v.u = ((uint32_t)h) << 16;
  return v.f;
}

// ---- fp8 e4m3 (OCP) encode/decode ----
__device__ __forceinline__ uint8_t enc_fp8(float f) {
#if __has_builtin(__builtin_amdgcn_cvt_pk_fp8_f32)
  int r = __builtin_amdgcn_cvt_pk_fp8_f32(f, f, 0, false);
  return (uint8_t)(r & 0xff);
#else
  __hip_fp8_e4m3 t(f);
  return t.__x;
#endif
}
__device__ __forceinline__ float dec_fp8_byte(uint32_t b) {
  uint32_t e = (b >> 3) & 15u, m = b & 7u, s = (b & 0x80u) << 24;
  union { uint32_t u; float f; } n; n.u = s | ((e + 120u) << 23) | (m << 20);
  union { uint32_t u; float f; } d; d.f = (float)m * 0x1p-9f; d.u |= s;
  return e ? n.f : d.f;
}

// ---------------- conversions ----------------
__global__ __launch_bounds__(256) void k_convert_x(const float* __restrict__ x,
                                                   ushort* __restrict__ xb) {
  long gid = (long)blockIdx.x * blockDim.x + threadIdx.x;
  long idx = gid * 8;
  if (idx >= (long)MPAD * NFEAT) return;
  int row = (int)(idx >> 9);
  short8 o;
  if (row < N_NODES) {
    const float4* p = (const float4*)(x + idx);
    float4 a = p[0], b = p[1];
    o[0] = f2bf(a.x); o[1] = f2bf(a.y); o[2] = f2bf(a.z); o[3] = f2bf(a.w);
    o[4] = f2bf(b.x); o[5] = f2bf(b.y); o[6] = f2bf(b.z); o[7] = f2bf(b.w);
  } else {
    o = (short8)0;   // zero pad rows
  }
  *(short8*)(xb + idx) = o;
}

__global__ __launch_bounds__(256) void k_convert(const float* __restrict__ in,
                                                 ushort* __restrict__ out, int n8) {
  int gid = blockIdx.x * blockDim.x + threadIdx.x;
  if (gid >= n8) return;
  long idx = (long)gid * 8;
  const float4* p = (const float4*)(in + idx);
  float4 a = p[0], b = p[1];
  short8 o;
  o[0] = f2bf(a.x); o[1] = f2bf(a.y); o[2] = f2bf(a.z); o[3] = f2bf(a.w);
  o[4] = f2bf(b.x); o[5] = f2bf(b.y); o[6] = f2bf(b.z); o[7] = f2bf(b.w);
  *(short8*)(out + idx) = o;
}

// ---------------- CSR build (unordered segments) ----------------
__global__ __launch_bounds__(256) void k_hist(const int* __restrict__ src,
                                              int* __restrict__ deg) {
  int e = blockIdx.x * blockDim.x + threadIdx.x;
  if (e < N_EDGES) atomicAdd(&deg[src[e]], 1);
}

// per-node segment allocation: wave-aggregated atomic on a single counter.
// rpb[i]..rpe[i] is node i's segment; segments need not be ordered.
__global__ __launch_bounds__(256) void k_alloc(const int* __restrict__ deg,
                                               int* __restrict__ rpb,
                                               int* __restrict__ rpe,
                                               int* __restrict__ cur,
                                               int* __restrict__ counter) {
  int i = blockIdx.x * blockDim.x + threadIdx.x;
  int lane = threadIdx.x & 63;
  int d = (i < N_NODES) ? deg[i] : 0;
  int sc = d;
  #pragma unroll
  for (int off = 1; off < 64; off <<= 1) {
    int u = __shfl_up(sc, off, 64);
    if (lane >= off) sc += u;
  }
  int base = 0;
  if (lane == 63) base = atomicAdd(counter, sc);
  base = __shfl(base, 63, 64);
  if (i < N_NODES) {
    int start = base + sc - d;
    rpb[i] = start;
    rpe[i] = start + d;
    cur[i] = start;
  }
}

__global__ __launch_bounds__(256) void k_fill(const int* __restrict__ src,
                                              const int* __restrict__ dst,
                                              const float* __restrict__ w,
                                              int* __restrict__ cur,
                                              int* __restrict__ sdst,
                                              float* __restrict__ sw) {
  int e = blockIdx.x * blockDim.x + threadIdx.x;
  if (e < N_EDGES) {
    int s = src[e];
    int pos = atomicAdd(&cur[s], 1);
    sdst[pos] = dst[e];
    sw[pos] = w[e];
  }
}

// ---------------- GEMM: C = A @ B^T + bias (bf16 in, f32 acc) ----------------
// OUT_FP8=1: store e4m3 bytes; OUT_FP8=0: store bf16.
// A [M][K] bf16 row-major, B [Nout][K] bf16 row-major.
// tile 128x128, BK=64, 256 threads (4 waves, 2x2), each wave 64x64 = 4x4 frags.
template <int OUT_FP8>
__global__ __launch_bounds__(256) void k_gemm_bt(const ushort* __restrict__ A,
                                                 const ushort* __restrict__ B,
                                                 const float* __restrict__ bias,
                                                 void* __restrict__ Cout,
                                                 int K, int Nout) {
  __shared__ ushort sA[128 * 64];
  __shared__ ushort sB[128 * 64];
  const int t = threadIdx.x;
  const int lane = t & 63;
  const int wave = t >> 6;
  const int wr = wave >> 1, wc = wave & 1;
  const int bm = blockIdx.x, bn = blockIdx.y;

  f32x4 acc[4][4];
  #pragma unroll
  for (int i = 0; i < 4; i++)
    #pragma unroll
    for (int j = 0; j < 4; j++) acc[i][j] = (f32x4)0.f;

  const long a_base = (long)bm * 128 * K;
  const long b_base = (long)bn * 128 * K;

  for (int kt = 0; kt < K; kt += 64) {
    #pragma unroll
    for (int it = 0; it < 4; ++it) {
      int c = it * 256 + t;           // chunk 0..1023
      int r = c >> 3, cc = c & 7;     // row, 16B-chunk within row
      int swz = (cc * 16) ^ ((r & 7) << 4);
      float4 va = *(const float4*)(A + a_base + (long)r * K + kt + cc * 8);
      *(float4*)((char*)sA + r * 128 + swz) = va;
      float4 vb = *(const float4*)(B + b_base + (long)r * K + kt + cc * 8);
      *(float4*)((char*)sB + r * 128 + swz) = vb;
    }
    __syncthreads();
    #pragma unroll
    for (int kk = 0; kk < 2; ++kk) {
      short8 af[4], bfr[4];
      int kchunk = kk * 4 + (lane >> 4);
      #pragma unroll
      for (int mr = 0; mr < 4; ++mr) {
        int row = wr * 64 + mr * 16 + (lane & 15);
        af[mr] = *(const short8*)((const char*)sA + row * 128 +
                                  ((kchunk * 16) ^ ((row & 7) << 4)));
      }
      #pragma unroll
      for (int nr = 0; nr < 4; ++nr) {
        int row = wc * 64 + nr * 16 + (lane & 15);
        bfr[nr] = *(const short8*)((const char*)sB + row * 128 +
                                   ((kchunk * 16) ^ ((row & 7) << 4)));
      }
      #pragma unroll
      for (int mr = 0; mr < 4; ++mr)
        #pragma unroll
        for (int nr = 0; nr < 4; ++nr)
          acc[mr][nr] = __builtin_amdgcn_mfma_f32_16x16x32_bf16(af[mr], bfr[nr],
                                                                acc[mr][nr], 0, 0, 0);
    }
    __syncthreads();
  }

  // epilogue: +bias. C/D layout: col = lane&15, row = (lane>>4)*4 + reg
  #pragma unroll
  for (int mr = 0; mr < 4; ++mr)
    #pragma unroll
    for (int nr = 0; nr < 4; ++nr) {
      int col = bn * 128 + wc * 64 + nr * 16 + (lane & 15);
      float bv = bias[col];
      #pragma unroll
      for (int reg = 0; reg < 4; ++reg) {
        int row = bm * 128 + wr * 64 + mr * 16 + (lane >> 4) * 4 + reg;
        float val = acc[mr][nr][reg] + bv;
        if (OUT_FP8) {
          ((uint8_t*)Cout)[(long)row * Nout + col] = enc_fp8(val);
        } else {
          ((ushort*)Cout)[(long)row * Nout + col] = f2bf(val);
        }
      }
    }
}

// ---------------- SpMM layer 1 (+ReLU): fp8 gather -> bf16 out ----------------
// 2 nodes per 256-thread block; 128 threads per node; 4 feats (uchar4) per thread.
__global__ __launch_bounds__(256) void k_spmm1(const int* __restrict__ rpb,
                                               const int* __restrict__ rpe,
                                               const int* __restrict__ sdst,
                                               const float* __restrict__ sw,
                                               const uint8_t* __restrict__ c1,
                                               ushort* __restrict__ h) {
  int node = blockIdx.x * 2 + (threadIdx.x >> 7);
  int tt = threadIdx.x & 127;
  float a0 = 0.f, a1 = 0.f, a2 = 0.f, a3 = 0.f;
  if (node < N_NODES) {
    int beg = rpb[node], end = rpe[node];
    for (int j = beg; j < end; ++j) {
      int d = sdst[j];
      float w = sw[j];
      uint32_t v = *(const uint32_t*)(c1 + (long)d * NHID + 4 * tt);
#if __has_builtin(__builtin_amdgcn_cvt_pk_f32_fp8)
      f32x2 lo = __builtin_amdgcn_cvt_pk_f32_fp8(v, false);
      f32x2 hi = __builtin_amdgcn_cvt_pk_f32_fp8(v, true);
      a0 += w * lo[0]; a1 += w * lo[1]; a2 += w * hi[0]; a3 += w * hi[1];
#else
      a0 += w * dec_fp8_byte(v & 0xffu);
      a1 += w * dec_fp8_byte((v >> 8) & 0xffu);
      a2 += w * dec_fp8_byte((v >> 16) & 0xffu);
      a3 += w * dec_fp8_byte(v >> 24);
#endif
    }
  }
  a0 = a0 > 0.f ? a0 : 0.f;
  a1 = a1 > 0.f ? a1 : 0.f;
  a2 = a2 > 0.f ? a2 : 0.f;
  a3 = a3 > 0.f ? a3 : 0.f;
  ushort4 o;
  o.x = f2bf(a0); o.y = f2bf(a1); o.z = f2bf(a2); o.w = f2bf(a3);
  *(ushort4*)(h + (long)node * NHID + 4 * tt) = o;   // node < MPAD always
}

// ---------------- SpMM layer 2: bf16 gather -> f32 out ----------------
// 4 nodes per 256-thread block; wave per node; 2 classes (dword) per lane.
__global__ __launch_bounds__(256) void k_spmm2(const int* __restrict__ rpb,
                                               const int* __restrict__ rpe,
                                               const int* __restrict__ sdst,
                                               const float* __restrict__ sw,
                                               const ushort* __restrict__ c2,
                                               float* __restrict__ out) {
  int node = blockIdx.x * 4 + (threadIdx.x >> 6);
  int lane = threadIdx.x & 63;
  if (node >= N_NODES) return;
  float a0 = 0.f, a1 = 0.f;
  int beg = rpb[node], end = rpe[node];
  for (int j = beg; j < end; ++j) {
    int d = sdst[j];
    float w = sw[j];
    uint32_t v = *(const uint32_t*)(c2 + (long)d * NCLASS + 2 * lane);
    a0 += w * bf2f((ushort)(v & 0xffffu));
    a1 += w * bf2f((ushort)(v >> 16));
  }
  f32x2 st; st[0] = a0; st[1] = a1;
  *(f32x2*)(out + (long)node * NCLASS + 2 * lane) = st;
}

extern "C" void kernel_launch(void* const* d_in, const int* in_sizes, int n_in,
                              void* d_out, int out_size, void* d_ws, size_t ws_size,
                              hipStream_t stream) {
  const float* x    = (const float*)d_in[0];
  const float* ew   = (const float*)d_in[1];
  const float* W1   = (const float*)d_in[2];
  const float* b1   = (const float*)d_in[3];
  const float* W2   = (const float*)d_in[4];
  const float* b2   = (const float*)d_in[5];
  const int*   esrc = (const int*)d_in[6];
  const int*   edst = (const int*)d_in[7];
  float* out = (float*)d_out;

  char* ws = (char*)d_ws;
  size_t off = 0;
  auto alloc = [&](size_t bytes) -> void* {
    void* p = ws + off;
    off = (off + bytes + 255) & ~(size_t)255;
    return p;
  };

  ushort*  buf0 = (ushort*)alloc((size_t)MPAD * 512 * 2);  // x_bf16, later h_bf16
  ushort*  buf1 = (ushort*)alloc((size_t)MPAD * 512 * 2);  // c2_bf16
  uint8_t* c1f8 = (uint8_t*)alloc((size_t)MPAD * 512);     // c1 fp8
  ushort*  w1b  = (ushort*)alloc((size_t)512 * 512 * 2);
  ushort*  w2b  = (ushort*)alloc((size_t)128 * 512 * 2);
  int*     deg  = (int*)alloc((size_t)N_NODES * 4);
  int*     rpb  = (int*)alloc((size_t)N_NODES * 4);
  int*     rpe  = (int*)alloc((size_t)N_NODES * 4);
  int*     cur  = (int*)alloc((size_t)N_NODES * 4);
  int*     cnt  = (int*)alloc(256);
  int*     sdst = (int*)alloc((size_t)N_EDGES * 4);
  float*   sw   = (float*)alloc((size_t)N_EDGES * 4);

  // CSR build (unordered segments)
  hipMemsetAsync(deg, 0, (size_t)N_NODES * 4, stream);
  hipMemsetAsync(cnt, 0, 4, stream);
  k_hist<<<(N_EDGES + 255) / 256, 256, 0, stream>>>(esrc, deg);
  k_alloc<<<(N_NODES + 255) / 256, 256, 0, stream>>>(deg, rpb, rpe, cur, cnt);
  k_fill<<<(N_EDGES + 255) / 256, 256, 0, stream>>>(esrc, edst, ew, cur, sdst, sw);

  // bf16 conversions
  k_convert_x<<<(MPAD * NFEAT / 8 + 255) / 256, 256, 0, stream>>>(x, buf0);
  k_convert<<<(512 * 512 / 8 + 255) / 256, 256, 0, stream>>>(W1, w1b, 512 * 512 / 8);
  k_convert<<<(128 * 512 / 8 + 255) / 256, 256, 0, stream>>>(W2, w2b, 128 * 512 / 8);

  // layer 1: linear (fp8 out) -> spmm+relu (bf16 out)
  dim3 g1(MPAD / 128, NHID / 128);
  k_gemm_bt<1><<<g1, 256, 0, stream>>>(buf0, w1b, b1, c1f8, NFEAT, NHID);
  k_spmm1<<<MPAD / 2, 256, 0, stream>>>(rpb, rpe, sdst, sw, c1f8, buf0);

  // layer 2: linear (bf16 out) -> spmm (f32 out)
  dim3 g2(MPAD / 128, NCLASS / 128);
  k_gemm_bt<0><<<g2, 256, 0, stream>>>(buf0, w2b, b2, buf1, NHID, NCLASS);
  k_spmm2<<<(N_NODES + 3) / 4, 256, 0, stream>>>(rpb, rpe, sdst, sw, buf1, out);
}

// Round 6
// 296.959 us; speedup vs baseline: 1.6542x; 1.4327x over previous
//
#include <hip/hip_runtime.h>
#include <hip/hip_bf16.h>
#include <hip/hip_fp8.h>
#include <stdint.h>

#define N_NODES 50000
#define N_EDGES 800000
#define NFEAT 512
#define NHID 512
#define NCLASS 128
#define MPAD 50048   // 391 * 128

typedef short short8 __attribute__((ext_vector_type(8)));
typedef float f32x4 __attribute__((ext_vector_type(4)));
typedef float f32x2 __attribute__((ext_vector_type(2)));

__device__ __forceinline__ ushort f2bf(float f) {
  union { float f; uint32_t u; } v; v.f = f;
  uint32_t u = v.u;
  uint32_t r = (u + 0x7fffu + ((u >> 16) & 1u)) >> 16;  // RNE
  return (ushort)r;
}
__device__ __forceinline__ float bf2f(ushort h) {
  union { uint32_t u; float f; } v; v.u = ((uint32_t)h) << 16;
  return v.f;
}

// ---- fp8 e4m3 (OCP) encode/decode ----
__device__ __forceinline__ uint8_t enc_fp8(float f) {
#if __has_builtin(__builtin_amdgcn_cvt_pk_fp8_f32)
  int r = __builtin_amdgcn_cvt_pk_fp8_f32(f, f, 0, false);
  return (uint8_t)(r & 0xff);
#else
  __hip_fp8_e4m3 t(f);
  return t.__x;
#endif
}
__device__ __forceinline__ float dec_fp8_byte(uint32_t b) {
  uint32_t e = (b >> 3) & 15u, m = b & 7u, s = (b & 0x80u) << 24;
  union { uint32_t u; float f; } n; n.u = s | ((e + 120u) << 23) | (m << 20);
  union { uint32_t u; float f; } d; d.f = (float)m * 0x1p-9f; d.u |= s;
  return e ? n.f : d.f;
}

// decode 4 fp8 bytes in dword v, accumulate into a[0..3] with weight w
__device__ __forceinline__ void acc_fp8x4(float* a, uint32_t v, float w) {
#if __has_builtin(__builtin_amdgcn_cvt_pk_f32_fp8)
  f32x2 lo = __builtin_amdgcn_cvt_pk_f32_fp8(v, false);
  f32x2 hi = __builtin_amdgcn_cvt_pk_f32_fp8(v, true);
  a[0] += w * lo[0]; a[1] += w * lo[1]; a[2] += w * hi[0]; a[3] += w * hi[1];
#else
  a[0] += w * dec_fp8_byte(v & 0xffu);
  a[1] += w * dec_fp8_byte((v >> 8) & 0xffu);
  a[2] += w * dec_fp8_byte((v >> 16) & 0xffu);
  a[3] += w * dec_fp8_byte(v >> 24);
#endif
}

// ---------------- conversions ----------------
__global__ __launch_bounds__(256) void k_convert_x(const float* __restrict__ x,
                                                   ushort* __restrict__ xb) {
  long gid = (long)blockIdx.x * blockDim.x + threadIdx.x;
  long idx = gid * 8;
  if (idx >= (long)MPAD * NFEAT) return;
  int row = (int)(idx >> 9);
  short8 o;
  if (row < N_NODES) {
    const float4* p = (const float4*)(x + idx);
    float4 a = p[0], b = p[1];
    o[0] = f2bf(a.x); o[1] = f2bf(a.y); o[2] = f2bf(a.z); o[3] = f2bf(a.w);
    o[4] = f2bf(b.x); o[5] = f2bf(b.y); o[6] = f2bf(b.z); o[7] = f2bf(b.w);
  } else {
    o = (short8)0;   // zero pad rows
  }
  *(short8*)(xb + idx) = o;
}

__global__ __launch_bounds__(256) void k_convert(const float* __restrict__ in,
                                                 ushort* __restrict__ out, int n8) {
  int gid = blockIdx.x * blockDim.x + threadIdx.x;
  if (gid >= n8) return;
  long idx = (long)gid * 8;
  const float4* p = (const float4*)(in + idx);
  float4 a = p[0], b = p[1];
  short8 o;
  o[0] = f2bf(a.x); o[1] = f2bf(a.y); o[2] = f2bf(a.z); o[3] = f2bf(a.w);
  o[4] = f2bf(b.x); o[5] = f2bf(b.y); o[6] = f2bf(b.z); o[7] = f2bf(b.w);
  *(short8*)(out + idx) = o;
}

// ---------------- CSR build (unordered segments) ----------------
__global__ __launch_bounds__(256) void k_hist(const int* __restrict__ src,
                                              int* __restrict__ deg) {
  int e = blockIdx.x * blockDim.x + threadIdx.x;
  if (e < N_EDGES) atomicAdd(&deg[src[e]], 1);
}

__global__ __launch_bounds__(256) void k_alloc(const int* __restrict__ deg,
                                               int* __restrict__ rpb,
                                               int* __restrict__ rpe,
                                               int* __restrict__ cur,
                                               int* __restrict__ counter) {
  int i = blockIdx.x * blockDim.x + threadIdx.x;
  int lane = threadIdx.x & 63;
  int d = (i < N_NODES) ? deg[i] : 0;
  int sc = d;
  #pragma unroll
  for (int off = 1; off < 64; off <<= 1) {
    int u = __shfl_up(sc, off, 64);
    if (lane >= off) sc += u;
  }
  int base = 0;
  if (lane == 63) base = atomicAdd(counter, sc);
  base = __shfl(base, 63, 64);
  if (i < N_NODES) {
    int start = base + sc - d;
    rpb[i] = start;
    rpe[i] = start + d;
    cur[i] = start;
  }
}

__global__ __launch_bounds__(256) void k_fill(const int* __restrict__ src,
                                              const int* __restrict__ dst,
                                              const float* __restrict__ w,
                                              int* __restrict__ cur,
                                              int* __restrict__ sdst,
                                              float* __restrict__ sw) {
  int e = blockIdx.x * blockDim.x + threadIdx.x;
  if (e < N_EDGES) {
    int s = src[e];
    int pos = atomicAdd(&cur[s], 1);
    sdst[pos] = dst[e];
    sw[pos] = w[e];
  }
}

// ---------------- GEMM: C = A @ B^T + bias (bf16 in, f32 acc) ----------------
template <int OUT_FP8>
__global__ __launch_bounds__(256) void k_gemm_bt(const ushort* __restrict__ A,
                                                 const ushort* __restrict__ B,
                                                 const float* __restrict__ bias,
                                                 void* __restrict__ Cout,
                                                 int K, int Nout) {
  __shared__ ushort sA[128 * 64];
  __shared__ ushort sB[128 * 64];
  const int t = threadIdx.x;
  const int lane = t & 63;
  const int wave = t >> 6;
  const int wr = wave >> 1, wc = wave & 1;
  const int bm = blockIdx.x, bn = blockIdx.y;

  f32x4 acc[4][4];
  #pragma unroll
  for (int i = 0; i < 4; i++)
    #pragma unroll
    for (int j = 0; j < 4; j++) acc[i][j] = (f32x4)0.f;

  const long a_base = (long)bm * 128 * K;
  const long b_base = (long)bn * 128 * K;

  for (int kt = 0; kt < K; kt += 64) {
    #pragma unroll
    for (int it = 0; it < 4; ++it) {
      int c = it * 256 + t;           // chunk 0..1023
      int r = c >> 3, cc = c & 7;     // row, 16B-chunk within row
      int swz = (cc * 16) ^ ((r & 7) << 4);
      float4 va = *(const float4*)(A + a_base + (long)r * K + kt + cc * 8);
      *(float4*)((char*)sA + r * 128 + swz) = va;
      float4 vb = *(const float4*)(B + b_base + (long)r * K + kt + cc * 8);
      *(float4*)((char*)sB + r * 128 + swz) = vb;
    }
    __syncthreads();
    #pragma unroll
    for (int kk = 0; kk < 2; ++kk) {
      short8 af[4], bfr[4];
      int kchunk = kk * 4 + (lane >> 4);
      #pragma unroll
      for (int mr = 0; mr < 4; ++mr) {
        int row = wr * 64 + mr * 16 + (lane & 15);
        af[mr] = *(const short8*)((const char*)sA + row * 128 +
                                  ((kchunk * 16) ^ ((row & 7) << 4)));
      }
      #pragma unroll
      for (int nr = 0; nr < 4; ++nr) {
        int row = wc * 64 + nr * 16 + (lane & 15);
        bfr[nr] = *(const short8*)((const char*)sB + row * 128 +
                                   ((kchunk * 16) ^ ((row & 7) << 4)));
      }
      #pragma unroll
      for (int mr = 0; mr < 4; ++mr)
        #pragma unroll
        for (int nr = 0; nr < 4; ++nr)
          acc[mr][nr] = __builtin_amdgcn_mfma_f32_16x16x32_bf16(af[mr], bfr[nr],
                                                                acc[mr][nr], 0, 0, 0);
    }
    __syncthreads();
  }

  #pragma unroll
  for (int mr = 0; mr < 4; ++mr)
    #pragma unroll
    for (int nr = 0; nr < 4; ++nr) {
      int col = bn * 128 + wc * 64 + nr * 16 + (lane & 15);
      float bv = bias[col];
      #pragma unroll
      for (int reg = 0; reg < 4; ++reg) {
        int row = bm * 128 + wr * 64 + mr * 16 + (lane >> 4) * 4 + reg;
        float val = acc[mr][nr][reg] + bv;
        if (OUT_FP8) {
          ((uint8_t*)Cout)[(long)row * Nout + col] = enc_fp8(val);
        } else {
          ((ushort*)Cout)[(long)row * Nout + col] = f2bf(val);
        }
      }
    }
}

// ---------------- SpMM layer 1 (+ReLU): fp8 gather -> bf16 out ----------------
// wave per node (4 nodes / 256-block); lane reads 8B (8 feats) per edge; 4-deep unroll.
__global__ __launch_bounds__(256) void k_spmm1(const int* __restrict__ rpb,
                                               const int* __restrict__ rpe,
                                               const int* __restrict__ sdst,
                                               const float* __restrict__ sw,
                                               const uint8_t* __restrict__ c1,
                                               ushort* __restrict__ h) {
  int node = blockIdx.x * 4 + (threadIdx.x >> 6);   // < MPAD
  int lane = threadIdx.x & 63;
  float a[8] = {0.f, 0.f, 0.f, 0.f, 0.f, 0.f, 0.f, 0.f};
  if (node < N_NODES) {
    int beg = rpb[node], end = rpe[node];
    int j = beg;
    for (; j + 4 <= end; j += 4) {
      int d0 = sdst[j], d1 = sdst[j + 1], d2 = sdst[j + 2], d3 = sdst[j + 3];
      float w0 = sw[j], w1 = sw[j + 1], w2 = sw[j + 2], w3 = sw[j + 3];
      uint2 v0 = *(const uint2*)(c1 + (long)d0 * NHID + lane * 8);
      uint2 v1 = *(const uint2*)(c1 + (long)d1 * NHID + lane * 8);
      uint2 v2 = *(const uint2*)(c1 + (long)d2 * NHID + lane * 8);
      uint2 v3 = *(const uint2*)(c1 + (long)d3 * NHID + lane * 8);
      acc_fp8x4(a, v0.x, w0); acc_fp8x4(a + 4, v0.y, w0);
      acc_fp8x4(a, v1.x, w1); acc_fp8x4(a + 4, v1.y, w1);
      acc_fp8x4(a, v2.x, w2); acc_fp8x4(a + 4, v2.y, w2);
      acc_fp8x4(a, v3.x, w3); acc_fp8x4(a + 4, v3.y, w3);
    }
    for (; j < end; ++j) {
      int d = sdst[j];
      float w = sw[j];
      uint2 v = *(const uint2*)(c1 + (long)d * NHID + lane * 8);
      acc_fp8x4(a, v.x, w); acc_fp8x4(a + 4, v.y, w);
    }
  }
  short8 o;
  #pragma unroll
  for (int k = 0; k < 8; ++k) o[k] = (short)f2bf(a[k] > 0.f ? a[k] : 0.f);
  *(short8*)(h + (long)node * NHID + lane * 8) = o;
}

// ---------------- SpMM layer 2: bf16 gather -> f32 out ----------------
// wave per node; lane reads dword (2 classes) per edge; 4-deep unroll.
__global__ __launch_bounds__(256) void k_spmm2(const int* __restrict__ rpb,
                                               const int* __restrict__ rpe,
                                               const int* __restrict__ sdst,
                                               const float* __restrict__ sw,
                                               const ushort* __restrict__ c2,
                                               float* __restrict__ out) {
  int node = blockIdx.x * 4 + (threadIdx.x >> 6);
  int lane = threadIdx.x & 63;
  if (node >= N_NODES) return;
  float a0 = 0.f, a1 = 0.f;
  int beg = rpb[node], end = rpe[node];
  int j = beg;
  for (; j + 4 <= end; j += 4) {
    int d0 = sdst[j], d1 = sdst[j + 1], d2 = sdst[j + 2], d3 = sdst[j + 3];
    float w0 = sw[j], w1 = sw[j + 1], w2 = sw[j + 2], w3 = sw[j + 3];
    uint32_t v0 = *(const uint32_t*)(c2 + (long)d0 * NCLASS + 2 * lane);
    uint32_t v1 = *(const uint32_t*)(c2 + (long)d1 * NCLASS + 2 * lane);
    uint32_t v2 = *(const uint32_t*)(c2 + (long)d2 * NCLASS + 2 * lane);
    uint32_t v3 = *(const uint32_t*)(c2 + (long)d3 * NCLASS + 2 * lane);
    a0 += w0 * bf2f((ushort)(v0 & 0xffffu)); a1 += w0 * bf2f((ushort)(v0 >> 16));
    a0 += w1 * bf2f((ushort)(v1 & 0xffffu)); a1 += w1 * bf2f((ushort)(v1 >> 16));
    a0 += w2 * bf2f((ushort)(v2 & 0xffffu)); a1 += w2 * bf2f((ushort)(v2 >> 16));
    a0 += w3 * bf2f((ushort)(v3 & 0xffffu)); a1 += w3 * bf2f((ushort)(v3 >> 16));
  }
  for (; j < end; ++j) {
    int d = sdst[j];
    float w = sw[j];
    uint32_t v = *(const uint32_t*)(c2 + (long)d * NCLASS + 2 * lane);
    a0 += w * bf2f((ushort)(v & 0xffffu));
    a1 += w * bf2f((ushort)(v >> 16));
  }
  f32x2 st; st[0] = a0; st[1] = a1;
  *(f32x2*)(out + (long)node * NCLASS + 2 * lane) = st;
}

extern "C" void kernel_launch(void* const* d_in, const int* in_sizes, int n_in,
                              void* d_out, int out_size, void* d_ws, size_t ws_size,
                              hipStream_t stream) {
  const float* x    = (const float*)d_in[0];
  const float* ew   = (const float*)d_in[1];
  const float* W1   = (const float*)d_in[2];
  const float* b1   = (const float*)d_in[3];
  const float* W2   = (const float*)d_in[4];
  const float* b2   = (const float*)d_in[5];
  const int*   esrc = (const int*)d_in[6];
  const int*   edst = (const int*)d_in[7];
  float* out = (float*)d_out;

  char* ws = (char*)d_ws;
  size_t off = 0;
  auto alloc = [&](size_t bytes) -> void* {
    void* p = ws + off;
    off = (off + bytes + 255) & ~(size_t)255;
    return p;
  };

  ushort*  buf0 = (ushort*)alloc((size_t)MPAD * 512 * 2);  // x_bf16, later h_bf16
  ushort*  buf1 = (ushort*)alloc((size_t)MPAD * 512 * 2);  // c2_bf16
  uint8_t* c1f8 = (uint8_t*)alloc((size_t)MPAD * 512);     // c1 fp8
  ushort*  w1b  = (ushort*)alloc((size_t)512 * 512 * 2);
  ushort*  w2b  = (ushort*)alloc((size_t)128 * 512 * 2);
  int*     deg  = (int*)alloc((size_t)N_NODES * 4);
  int*     rpb  = (int*)alloc((size_t)N_NODES * 4);
  int*     rpe  = (int*)alloc((size_t)N_NODES * 4);
  int*     cur  = (int*)alloc((size_t)N_NODES * 4);
  int*     cnt  = (int*)alloc(256);
  int*     sdst = (int*)alloc((size_t)N_EDGES * 4);
  float*   sw   = (float*)alloc((size_t)N_EDGES * 4);

  // CSR build (unordered segments)
  hipMemsetAsync(deg, 0, (size_t)N_NODES * 4, stream);
  hipMemsetAsync(cnt, 0, 4, stream);
  k_hist<<<(N_EDGES + 255) / 256, 256, 0, stream>>>(esrc, deg);
  k_alloc<<<(N_NODES + 255) / 256, 256, 0, stream>>>(deg, rpb, rpe, cur, cnt);
  k_fill<<<(N_EDGES + 255) / 256, 256, 0, stream>>>(esrc, edst, ew, cur, sdst, sw);

  // bf16 conversions
  k_convert_x<<<(MPAD * NFEAT / 8 + 255) / 256, 256, 0, stream>>>(x, buf0);
  k_convert<<<(512 * 512 / 8 + 255) / 256, 256, 0, stream>>>(W1, w1b, 512 * 512 / 8);
  k_convert<<<(128 * 512 / 8 + 255) / 256, 256, 0, stream>>>(W2, w2b, 128 * 512 / 8);

  // layer 1: linear (fp8 out) -> spmm+relu (bf16 out)
  dim3 g1(MPAD / 128, NHID / 128);
  k_gemm_bt<1><<<g1, 256, 0, stream>>>(buf0, w1b, b1, c1f8, NFEAT, NHID);
  k_spmm1<<<MPAD / 4, 256, 0, stream>>>(rpb, rpe, sdst, sw, c1f8, buf0);

  // layer 2: linear (bf16 out) -> spmm (f32 out)
  dim3 g2(MPAD / 128, NCLASS / 128);
  k_gemm_bt<0><<<g2, 256, 0, stream>>>(buf0, w2b, b2, buf1, NHID, NCLASS);
  k_spmm2<<<(N_NODES + 3) / 4, 256, 0, stream>>>(rpb, rpe, sdst, sw, buf1, out);
}